// Round 5
// baseline (186.220 us; speedup 1.0000x reference)
//
#include <hip/hip_runtime.h>
#include <math.h>

#define LVL 16
#define TBL 65536
#define BATCH 8
#define NPIX 65536       // 256*256
#define SDIM 512
#define HPRIME 2654435761u

#define NROWS 4          // rows per fused block (double-buffered pipeline)
#define MAXCUM 1472      // capacity for sum(R_l) ~= 1440 (+ rounding slack)
#define FITERS 6         // ceil(MAXCUM+/256)

typedef __attribute__((ext_vector_type(2))) float f32x2;

struct ResPack { int r[LVL]; };
struct OffPack { int o[LVL]; };

// ws layout (floats): [0, 17152) weff (8 batches x 2144 paired layout),
// [17152, +736) fill plan as u16[1472] (2944 B). Total 71552 B <= 71680 B.
#define WEFF_STRIDE 2144
#define PLAN_OFF    17152

// ---------------------------------------------------------------------------
// Kernel A: fused style + demod + weff emit (verified round-1 structure),
// plus: block 0 writes the flat fill plan (flat idx -> level|x) into ws.
// ---------------------------------------------------------------------------
__global__ __launch_bounds__(256) void weff_kernel(
    const float* __restrict__ s,
    const float* __restrict__ aw0, const float* __restrict__ ab0,
    const float* __restrict__ aw1, const float* __restrict__ ab1,
    const float* __restrict__ aw2, const float* __restrict__ ab2,
    const float* __restrict__ w0, const float* __restrict__ w1,
    const float* __restrict__ w2,
    float* __restrict__ ws, OffPack op, int cum)
{
    const int b = blockIdx.x & 7;
    const int l = blockIdx.x >> 3;
    const int tid = (int)threadIdx.x;
    const int wave = tid >> 6, lane = tid & 63;

    // ---- plan generation (block 0 only; independent of the rest) ----
    if (blockIdx.x == 0) {
        unsigned short* plan = (unsigned short*)(ws + PLAN_OFF);
        for (int i = tid; i < cum; i += 256) {
            int lv = 0, base = 0;
            #pragma unroll
            for (int t = 1; t < LVL; ++t) {
                if (i >= op.o[t]) { lv = t; base = op.o[t]; }
            }
            plan[i] = (unsigned short)((lv << 8) | (i - base));
        }
    }

    const float* aw; const float* ab; const float* w; int nout;
    if (l == 0)      { aw = aw0; ab = ab0; w = w0; nout = 32; }
    else if (l == 1) { aw = aw1; ab = ab1; w = w1; nout = 32; }
    else             { aw = aw2; ab = ab2; w = w2; nout = 3;  }

    __shared__ float st[32];
    __shared__ float dem[32];

    // ---- style: 32 rows x dot(512). 4 waves x 8 rows, 2 chains per iter.
    const float* sb = s + b * SDIM;
    for (int r0 = wave * 8; r0 < wave * 8 + 8; r0 += 2) {
        const float* rowA = aw + (size_t)r0 * SDIM;
        const float* rowB = aw + (size_t)(r0 + 1) * SDIM;
        float a0 = 0.f, a1 = 0.f;
        #pragma unroll
        for (int j = 0; j < SDIM / 64; ++j) {
            const int k = lane + j * 64;
            const float sv = sb[k];
            a0 += sv * rowA[k];
            a1 += sv * rowB[k];
        }
        #pragma unroll
        for (int off = 32; off >= 1; off >>= 1) {
            a0 += __shfl_xor(a0, off, 64);
            a1 += __shfl_xor(a1, off, 64);
        }
        if (lane == 0) { st[r0] = a0 + ab[r0]; st[r0 + 1] = a1 + ab[r0 + 1]; }
    }
    __syncthreads();

    // ---- demod: o = tid>>3 (0..31), 8 lanes each sum 4 squares + butterfly.
    {
        const int o = tid >> 3, sub = tid & 7;
        if (o < nout) {
            float sum = 0.f;
            #pragma unroll
            for (int j = 0; j < 4; ++j) {
                const int i = sub * 4 + j;
                const float v = w[o * 32 + i] * st[i];
                sum += v * v;
            }
            sum += __shfl_xor(sum, 4, 64);
            sum += __shfl_xor(sum, 2, 64);
            sum += __shfl_xor(sum, 1, 64);
            if (sub == 0) dem[o] = 1.0f / sqrtf(sum + 1e-8f);
        }
    }
    __syncthreads();

    // ---- emit paired layout (same formulas/order as the verified kernel).
    float* outp = ws + (size_t)b * WEFF_STRIDE;
    if (l < 2) {
        const int base = l * 1024;
        for (int idx = tid; idx < 1024; idx += 256) {
            const int o2 = idx >> 6, rem = idx & 63, i = rem >> 1, h = rem & 1;
            const int oo = o2 + 16 * h;
            outp[base + idx] = w[oo * 32 + i] * st[i] * dem[oo];
        }
    } else {
        if (tid < 96) {
            const int oo = tid >> 5, i = tid & 31;
            outp[2048 + tid] = w[tid] * st[i] * dem[oo];
        }
    }
}

// ---------------------------------------------------------------------------
// Kernel B: pre-blend hash-grid + MLP, row-pipelined.
// One block = one batch x NROWS consecutive image rows.
// Fill is flattened & balanced (plan-driven, ~6 iters x 2 gathers / thread),
// loads issued EARLY (batched into regs) and LDS-written LATE, double-buffered
// so row r+1's gathers hide under row r's MLP. MLP = verified packed-fp32.
// ---------------------------------------------------------------------------
__global__ __launch_bounds__(256) void fused_kernel(
    const float* __restrict__ tables,   // [B, L, T, 2]
    const float* __restrict__ coords,   // [N, 2]
    const float* __restrict__ weff,     // ws: paired weights per batch
    const unsigned short* __restrict__ plan,
    const float* __restrict__ b0, const float* __restrict__ b1, const float* __restrict__ b2,
    float* __restrict__ out,            // [B, 3, 256, 256]
    ResPack rp, OffPack op, int cum)
{
    const int b    = blockIdx.x & 7;            // XCD-affinity: batch <-> XCD
    const int grp  = blockIdx.x >> 3;
    const int tid  = (int)threadIdx.x;
    const int row0 = grp * NROWS;

    __shared__ float2 blend[2][MAXCUM];         // 23552 B
    __shared__ float rm1t[LVL];

    const float2* tb2 = (const float2*)tables + (size_t)b * (LVL * TBL);

    // ---- prologue: per-level consts, plan entries, per-row coords ----
    if (tid == 0) {
        #pragma unroll
        for (int l = 0; l < LVL; ++l) rm1t[l] = (float)(rp.r[l] - 1);
    }
    unsigned short pe[FITERS];
    #pragma unroll
    for (int k = 0; k < FITERS; ++k) {
        const int i = k * 256 + tid;
        pe[k] = (i < cum) ? plan[i] : (unsigned short)0;
    }
    float cyv[NROWS], cxv[NROWS];
    #pragma unroll
    for (int r = 0; r < NROWS; ++r) {
        cyv[r] = coords[((row0 + r) << 9) + 1];
        cxv[r] = coords[((row0 + r) << 9) + 2 * tid];
    }
    __syncthreads();

    int lvv[FITERS], xxv[FITERS];
    float rm1v[FITERS];
    #pragma unroll
    for (int k = 0; k < FITERS; ++k) {
        lvv[k]  = pe[k] >> 8;
        xxv[k]  = pe[k] & 255;
        rm1v[k] = rm1t[lvv[k]];
    }

    float2 g0v[FITERS], g1v[FITERS];
    float  fyv[FITERS];

// Issue all gathers for one row into registers (one batched vmcnt region).
#define FILL_ISSUE(CY) do {                                                    \
    _Pragma("unroll")                                                          \
    for (int k = 0; k < FITERS; ++k) {                                         \
        const float rm1 = rm1v[k];                                             \
        const float py  = (CY) * rm1;                                          \
        const float fpy = floorf(py);                                          \
        fyv[k] = py - fpy;                                                     \
        int y0 = (int)fpy;                                                     \
        int y1 = y0 + 1; const int ym = (int)rm1; if (y1 > ym) y1 = ym;        \
        const unsigned h0 = ((unsigned)xxv[k] ^ ((unsigned)y0 * HPRIME)) & 0xFFFFu; \
        const unsigned h1 = ((unsigned)xxv[k] ^ ((unsigned)y1 * HPRIME)) & 0xFFFFu; \
        const int base = lvv[k] << 16;                                         \
        if (k * 256 + tid < cum) {                                             \
            g0v[k] = tb2[base + (int)h0];                                      \
            g1v[k] = tb2[base + (int)h1];                                      \
        }                                                                      \
    }                                                                          \
} while (0)

// Lerp + LDS write (done AFTER the compute that overlaps the load latency).
#define FILL_WRITE(BUF) do {                                                   \
    _Pragma("unroll")                                                          \
    for (int k = 0; k < FITERS; ++k) {                                         \
        const int i = k * 256 + tid;                                           \
        if (i < cum) {                                                         \
            const float fy = fyv[k]; const float ofy = 1.f - fy;               \
            float2 rr;                                                         \
            rr.x = g0v[k].x * ofy + g1v[k].x * fy;                             \
            rr.y = g0v[k].y * ofy + g1v[k].y * fy;                             \
            blend[BUF][i] = rr;                                                \
        }                                                                      \
    }                                                                          \
} while (0)

    // ---- prologue fill: row 0 into buffer 0 ----
    FILL_ISSUE(cyv[0]);
    FILL_WRITE(0);
    __syncthreads();

    const f32x2* W0p = (const f32x2*)(weff + (size_t)b * WEFF_STRIDE);         // [16][32]
    const f32x2* W1p = W0p + 512;                                              // [16][32]
    const float* W2  = weff + (size_t)b * WEFF_STRIDE + 2048;                  // [3][32]

    #pragma unroll
    for (int r = 0; r < NROWS; ++r) {
        const int cur = r & 1;

        // prefetch next row's gathers (loads in flight across the MLP below)
        if (r + 1 < NROWS) FILL_ISSUE(cyv[r + 1]);

        // ---- per-pixel: x-interp from pre-blended LDS row ----
        const float2* bp = blend[cur];
        const float cx = cxv[r];
        float feat[32];
        #pragma unroll
        for (int l = 0; l < LVL; ++l) {
            const int R = rp.r[l];
            const float rm1 = (float)(R - 1);
            const float px  = cx * rm1;
            const float fpx = floorf(px);
            const float fx  = px - fpx;
            int x0 = (int)fpx;
            int x1 = x0 + 1; if (x1 > R - 1) x1 = R - 1;
            const int base = op.o[l];
            const float2 gA = bp[base + x0];
            const float2 gB = bp[base + x1];
            const float ofx = 1.f - fx;
            feat[2 * l]     = gA.x * ofx + gB.x * fx;
            feat[2 * l + 1] = gA.y * ofx + gB.y * fx;
        }

        // ---- MLP (verified paired-packed fp32 path, unchanged) ----
        f32x2 h1p[16];
        #pragma unroll
        for (int o2 = 0; o2 < 16; ++o2) {
            f32x2 acc; acc[0] = b0[o2]; acc[1] = b0[o2 + 16];
            #pragma unroll
            for (int i = 0; i < 32; ++i) {
                f32x2 fb; fb[0] = feat[i]; fb[1] = feat[i];
                acc += W0p[o2 * 32 + i] * fb;
            }
            acc[0] = fmaxf(acc[0], 0.f); acc[1] = fmaxf(acc[1], 0.f);
            h1p[o2] = acc;
        }

        f32x2 h2p[16];
        #pragma unroll
        for (int o2 = 0; o2 < 16; ++o2) {
            f32x2 acc; acc[0] = b1[o2]; acc[1] = b1[o2 + 16];
            #pragma unroll
            for (int i = 0; i < 32; ++i) {
                const float hv = h1p[i & 15][i >> 4];
                f32x2 fb; fb[0] = hv; fb[1] = hv;
                acc += W1p[o2 * 32 + i] * fb;
            }
            acc[0] = fmaxf(acc[0], 0.f); acc[1] = fmaxf(acc[1], 0.f);
            h2p[o2] = acc;
        }

        const int n = (row0 + r) * 256 + tid;
        #pragma unroll
        for (int o = 0; o < 3; ++o) {
            float acc = b2[o];
            #pragma unroll
            for (int i = 0; i < 32; ++i)
                acc = fmaf(W2[o * 32 + i], h2p[i & 15][i >> 4], acc);
            out[((size_t)(b * 3 + o) << 16) + n] = tanhf(acc);
        }

        // ---- write next row's blend (vmcnt drains here, latency now hidden)
        if (r + 1 < NROWS) FILL_WRITE(cur ^ 1);
        __syncthreads();
    }
#undef FILL_ISSUE
#undef FILL_WRITE
}

// ---------------------------------------------------------------------------
extern "C" void kernel_launch(void* const* d_in, const int* in_sizes, int n_in,
                              void* d_out, int out_size, void* d_ws, size_t ws_size,
                              hipStream_t stream) {
    const float* x      = (const float*)d_in[0];
    const float* s      = (const float*)d_in[1];
    const float* coords = (const float*)d_in[2];
    const float* w0  = (const float*)d_in[3];
    const float* aw0 = (const float*)d_in[4];
    const float* ab0 = (const float*)d_in[5];
    const float* b0  = (const float*)d_in[6];
    const float* w1  = (const float*)d_in[7];
    const float* aw1 = (const float*)d_in[8];
    const float* ab1 = (const float*)d_in[9];
    const float* b1  = (const float*)d_in[10];
    const float* w2  = (const float*)d_in[11];
    const float* aw2 = (const float*)d_in[12];
    const float* ab2 = (const float*)d_in[13];
    const float* b2  = (const float*)d_in[14];
    float* out = (float*)d_out;
    float* ws  = (float*)d_ws;    // usage: 71552 B

    ResPack rp; OffPack op;
    const double g = pow(256.0 / 16.0, 1.0 / 15.0);
    int cum = 0;
    for (int l = 0; l < LVL; ++l) {
        double r = 16.0 * pow(g, (double)l);
        long ri = lround(r);
        if (ri > 256) ri = 256;
        rp.r[l] = (int)ri;
        op.o[l] = cum;
        cum += (int)ri;
    }

    hipLaunchKernelGGL(weff_kernel, dim3(24), dim3(256), 0, stream,
                       s, aw0, ab0, aw1, ab1, aw2, ab2, w0, w1, w2, ws, op, cum);
    hipLaunchKernelGGL(fused_kernel, dim3((256 / NROWS) * BATCH), dim3(256), 0, stream,
                       x, coords, ws,
                       (const unsigned short*)(ws + PLAN_OFF),
                       b0, b1, b2, out, rp, op, cum);
}